// Round 12
// baseline (332.175 us; speedup 1.0000x reference)
//
#include <hip/hip_runtime.h>
#include <hip/hip_fp16.h>

#define N_NODES 100000
#define KN 32
#define EPS 1e-5f
#define NSLOT 128

// ---------------- workspace layout (float offsets) ----------------
#define OFF_X0   0          // [100000]   normalized scalar input
#define OFF_XEH  500000     // [100000*24 ushorts] packed fp16 xe2 rows: 18 xe, 2 pad, 3 q, pad
#define OFF_Z1Q  1800000    // [100000*8 ushorts] layer1 records: x0,S0,S1,S2,q0,q1,q2,pad
#define OFF_S4   2500000    // [100000*4] layer0 per-head weighted sums (float4)
#define OFF_X2   2900000    // [100000*18] layer1 raw output (fp32)
#define OFF_Y    4700000    // [100000*18] layer2 raw output (fp32)
#define OFF_TX   6500000    // [16]   x sum/ss
#define OFF_SS   6500016    // [128*8]  S slotted stats
#define OFF_X2S  6501040    // [128*36] x2 slotted stats
#define OFF_YS   6505648    // [128*36] y slotted stats
#define OFF_END  6510256

__device__ inline float2 h2f2(unsigned int w) {
    __half2 h = *reinterpret_cast<__half2*>(&w);
    return __half22float2(h);
}

// ---------------- stats of scalar input x (vectorized) ----------------
__global__ __launch_bounds__(256)
void statsx_kernel(const float4* __restrict__ x4, float* __restrict__ acc) {
    int i = blockIdx.x * 256 + threadIdx.x;
    float s = 0.f, ss = 0.f;
    if (i < 25000) {
        float4 v = x4[i];
        s = v.x + v.y + v.z + v.w;
        ss = v.x * v.x + v.y * v.y + v.z * v.z + v.w * v.w;
    }
#pragma unroll
    for (int off = 32; off > 0; off >>= 1) {
        s  += __shfl_xor(s,  off, 64);
        ss += __shfl_xor(ss, off, 64);
    }
    __shared__ float ls[4], lss[4];
    int wid = threadIdx.x >> 6;
    if ((threadIdx.x & 63) == 0) { ls[wid] = s; lss[wid] = ss; }
    __syncthreads();
    if (threadIdx.x == 0) {
        atomicAdd(&acc[0], ls[0] + ls[1] + ls[2] + ls[3]);
        atomicAdd(&acc[1], lss[0] + lss[1] + lss[2] + lss[3]);
    }
}

// ---------------- x0 = BN0(x), inline prep0 scale ----------------
__global__ __launch_bounds__(256)
void x0_kernel(const float4* __restrict__ x4, const float* __restrict__ TX,
               const float* __restrict__ g0, const float* __restrict__ be0,
               float4* __restrict__ x0) {
    __shared__ float ss0, st0;
    if (threadIdx.x == 0) {
        float mu  = TX[0] / (float)N_NODES;
        float var = TX[1] / (float)N_NODES - mu * mu;
        float s0 = rsqrtf(var + EPS) * g0[0];
        ss0 = s0; st0 = be0[0] - mu * s0;
    }
    __syncthreads();
    int i = blockIdx.x * blockDim.x + threadIdx.x;
    if (i < 25000) {
        float4 v = x4[i];
        float s = ss0, t = st0;
        x0[i] = make_float4(fmaf(v.x, s, t), fmaf(v.y, s, t), fmaf(v.z, s, t), fmaf(v.w, s, t));
    }
}

// ---------------- layer0 attention + fused S stats (inline score consts) ----------------
__global__ __launch_bounds__(256)
void att0_kernel(const float* __restrict__ x0,
                 const int* __restrict__ ei0, const int* __restrict__ ei1,
                 const float2* __restrict__ e2,
                 const float* __restrict__ W0, const float* __restrict__ b0,
                 const float* __restrict__ aW0, const float* __restrict__ ab0,
                 float4* __restrict__ S4, float* __restrict__ SS) {
    __shared__ float sC[11];   // A[3], B[3], C[3], ew0, ew1
    if (threadIdx.x == 0) {
        for (int h = 0; h < 3; ++h) {
            float A = 0.f, B = 0.f, Cc = 0.f;
            for (int f = 0; f < 6; ++f) {
                A  = fmaf(W0[h * 6 + f], aW0[f], A);
                B  = fmaf(W0[h * 6 + f], aW0[6 + f], B);
                Cc = fmaf(b0[h * 6 + f], aW0[f] + aW0[6 + f], Cc);
            }
            sC[h] = A; sC[3 + h] = B; sC[6 + h] = Cc + ab0[0];
        }
        sC[9] = aW0[12]; sC[10] = aW0[13];
    }
    __syncthreads();
    int hw = threadIdx.x >> 5;
    int node = blockIdx.x * 8 + hw;          // grid exactly N/8
    int k = threadIdx.x & 31;
    int eidx = node * KN + k;
    int s = ei0[eidx], d = ei1[eidx];
    float xs = x0[s], xd = x0[d];
    float2 ef = e2[eidx];
    float eb = fmaf(ef.x, sC[9], ef.y * sC[10]);
    float sc0 = fmaf(xs, sC[0], fmaf(xd, sC[3], sC[6] + eb));
    float sc1 = fmaf(xs, sC[1], fmaf(xd, sC[4], sC[7] + eb));
    float sc2 = fmaf(xs, sC[2], fmaf(xd, sC[5], sC[8] + eb));
    float m0 = sc0, m1 = sc1, m2 = sc2;
#pragma unroll
    for (int off = 16; off > 0; off >>= 1) {
        m0 = fmaxf(m0, __shfl_xor(m0, off, 32));
        m1 = fmaxf(m1, __shfl_xor(m1, off, 32));
        m2 = fmaxf(m2, __shfl_xor(m2, off, 32));
    }
    float w0 = __expf(sc0 - m0), w1 = __expf(sc1 - m1), w2 = __expf(sc2 - m2);
    float l0 = w0, l1 = w1, l2 = w2;
    float a0 = w0 * xs, a1 = w1 * xs, a2 = w2 * xs;
#pragma unroll
    for (int off = 16; off > 0; off >>= 1) {
        l0 += __shfl_xor(l0, off, 32); a0 += __shfl_xor(a0, off, 32);
        l1 += __shfl_xor(l1, off, 32); a1 += __shfl_xor(a1, off, 32);
        l2 += __shfl_xor(l2, off, 32); a2 += __shfl_xor(a2, off, 32);
    }
    __shared__ float sS[8][4];
    if (k == 0) {
        float v0 = a0 / l0, v1 = a1 / l1, v2 = a2 / l2;
        S4[node] = make_float4(v0, v1, v2, 0.f);
        sS[hw][0] = v0; sS[hw][1] = v1; sS[hw][2] = v2;
    }
    __syncthreads();
    if (threadIdx.x < 3) {
        float ps = 0.f, pss = 0.f;
#pragma unroll
        for (int h = 0; h < 8; ++h) { float v = sS[h][threadIdx.x]; ps += v; pss = fmaf(v, v, pss); }
        int slot = (blockIdx.x & (NSLOT - 1)) * 8;
        atomicAdd(&SS[slot + threadIdx.x], ps);
        atomicAdd(&SS[slot + 4 + threadIdx.x], pss);
    }
}

// ---------------- shared prep1 builder (M1, c1 from SS + weights) ----------------
__device__ inline void build_prep1(const float* __restrict__ SS,
                                   const float* __restrict__ W0,
                                   const float* __restrict__ g1, const float* __restrict__ be1,
                                   const float* __restrict__ W1, const float* __restrict__ b1,
                                   float muS[3], float varS[3], float alpha[18], float beta[18],
                                   float sM1[4][18], float sc1[18]) {
    int t = threadIdx.x;
    if (t < 3) {
        float s = 0.f, ss = 0.f;
#pragma unroll 8
        for (int i = 0; i < NSLOT; ++i) { s += SS[i * 8 + t]; ss += SS[i * 8 + 4 + t]; }
        float mu = s / (float)N_NODES;
        muS[t] = mu; varS[t] = ss / (float)N_NODES - mu * mu;
    }
    __syncthreads();
    if (t < 18) {
        int h = t / 6;
        float w = W0[t] / (float)KN;
        float inv1 = rsqrtf(varS[h] * w * w + EPS);
        float gg = inv1 * g1[t];
        alpha[t] = w * gg;
        beta[t]  = be1[t] - w * gg * muS[h];
    }
    __syncthreads();
    if (t < 18) {
        int j = t;
        sM1[0][j] = W1[j];
        for (int h = 0; h < 3; ++h) {
            float acc = 0.f;
            for (int f = 0; f < 6; ++f) acc = fmaf(alpha[h * 6 + f], W1[(1 + h * 6 + f) * 18 + j], acc);
            sM1[1 + h][j] = acc;
        }
        float cc = b1[j];
        for (int c = 0; c < 18; ++c) cc = fmaf(beta[c], W1[(1 + c) * 18 + j], cc);
        sc1[j] = cc;
    }
    __syncthreads();
}

// ---------------- zq1: pack [x0,S0,S1,S2,q0,q1,q2,pad] fp16, inline prep1 ----------------
__global__ __launch_bounds__(256)
void zq1_kernel(const float* __restrict__ x0, const float4* __restrict__ S4,
                const float* __restrict__ SS,
                const float* __restrict__ W0, const float* __restrict__ g1,
                const float* __restrict__ be1, const float* __restrict__ W1,
                const float* __restrict__ b1, const float* __restrict__ aW1,
                uint4* __restrict__ z1q1) {
    __shared__ float muS[3], varS[3], alpha[18], beta[18], sM1[4][18], sc1[18];
    build_prep1(SS, W0, g1, be1, W1, b1, muS, varS, alpha, beta, sM1, sc1);
    int n = blockIdx.x * blockDim.x + threadIdx.x;
    if (n >= N_NODES) return;
    float xv = x0[n];
    float4 S = S4[n];
    float row[18];
#pragma unroll
    for (int j = 0; j < 18; ++j) {
        float r = sc1[j];
        r = fmaf(xv,  sM1[0][j], r);
        r = fmaf(S.x, sM1[1][j], r);
        r = fmaf(S.y, sM1[2][j], r);
        r = fmaf(S.z, sM1[3][j], r);
        row[j] = r;
    }
    float q0 = 0.f, q1 = 0.f, q2 = 0.f;
#pragma unroll
    for (int f = 0; f < 6; ++f) {
        float a = aW1[6 + f];
        q0 = fmaf(row[f], a, q0);
        q1 = fmaf(row[6 + f], a, q1);
        q2 = fmaf(row[12 + f], a, q2);
    }
    union { unsigned short u[8]; uint4 v; } pk;
    pk.u[0] = __half_as_ushort(__float2half(xv));
    pk.u[1] = __half_as_ushort(__float2half(S.x));
    pk.u[2] = __half_as_ushort(__float2half(S.y));
    pk.u[3] = __half_as_ushort(__float2half(S.z));
    pk.u[4] = __half_as_ushort(__float2half(q0));
    pk.u[5] = __half_as_ushort(__float2half(q1));
    pk.u[6] = __half_as_ushort(__float2half(q2));
    pk.u[7] = 0;
    z1q1[n] = pk.v;
}

// ---------------- layer1 attention on z-records, inline prep1+PM ----------------
__global__ __launch_bounds__(256)
void att_z1_kernel(const uint4* __restrict__ z1q1,
                   const int* __restrict__ ei0, const int* __restrict__ ei1,
                   const float* __restrict__ SS,
                   const float* __restrict__ W0, const float* __restrict__ g1,
                   const float* __restrict__ be1, const float* __restrict__ W1,
                   const float* __restrict__ b1, const float* __restrict__ aW1,
                   const float* __restrict__ ab1,
                   float* __restrict__ out, float* __restrict__ slots) {
    __shared__ float muS[3], varS[3], alpha[18], beta[18], sM1[4][18], sc1[18];
    __shared__ float sPM[12], spc[3];
    build_prep1(SS, W0, g1, be1, W1, b1, muS, varS, alpha, beta, sM1, sc1);
    int t = threadIdx.x;
    if (t < 12) {                       // PM[c*3+h] = sum_f M1[c][h*6+f]*aW1[f]
        int c = t / 3, h = t - c * 3;
        float acc = 0.f;
        for (int f = 0; f < 6; ++f) acc = fmaf(sM1[c][h * 6 + f], aW1[f], acc);
        sPM[c * 3 + h] = acc;
    } else if (t < 15) {                // pc[h] = sum_f c1[h*6+f]*aW1[f] + ab1
        int h = t - 12;
        float acc = ab1[0];
        for (int f = 0; f < 6; ++f) acc = fmaf(sc1[h * 6 + f], aW1[f], acc);
        spc[h] = acc;
    }
    __syncthreads();
    int hw = threadIdx.x >> 5;
    int node = blockIdx.x * 8 + hw;          // grid exactly N/8
    int k = threadIdx.x & 31;
    int eidx = node * KN + k;
    int s = ei0[eidx], d = ei1[eidx];
    uint4 Rs = z1q1[s];
    uint4 Rd = z1q1[d];
    float2 z01 = h2f2(Rs.x), z23 = h2f2(Rs.y);
    float zc0 = z01.x, zc1 = z01.y, zc2 = z23.x, zc3 = z23.y;
    float2 q01 = h2f2(Rd.z), q23 = h2f2(Rd.w);
    float sc0 = spc[0] + q01.x, sc1v = spc[1] + q01.y, sc2 = spc[2] + q23.x;
    sc0  = fmaf(zc0, sPM[0], fmaf(zc1, sPM[3], fmaf(zc2, sPM[6], fmaf(zc3, sPM[9],  sc0))));
    sc1v = fmaf(zc0, sPM[1], fmaf(zc1, sPM[4], fmaf(zc2, sPM[7], fmaf(zc3, sPM[10], sc1v))));
    sc2  = fmaf(zc0, sPM[2], fmaf(zc1, sPM[5], fmaf(zc2, sPM[8], fmaf(zc3, sPM[11], sc2))));
    float m0 = sc0, m1 = sc1v, m2 = sc2;
#pragma unroll
    for (int off = 16; off > 0; off >>= 1) {
        m0 = fmaxf(m0, __shfl_xor(m0, off, 32));
        m1 = fmaxf(m1, __shfl_xor(m1, off, 32));
        m2 = fmaxf(m2, __shfl_xor(m2, off, 32));
    }
    float w0 = __expf(sc0 - m0), w1 = __expf(sc1v - m1), w2 = __expf(sc2 - m2);
    float l0 = w0, l1 = w1, l2 = w2;
    float A[3][4];
#pragma unroll
    for (int c = 0; c < 4; ++c) {
        float z = (c == 0) ? zc0 : (c == 1) ? zc1 : (c == 2) ? zc2 : zc3;
        A[0][c] = w0 * z; A[1][c] = w1 * z; A[2][c] = w2 * z;
    }
#pragma unroll
    for (int off = 16; off > 0; off >>= 1) {
        l0 += __shfl_xor(l0, off, 32);
        l1 += __shfl_xor(l1, off, 32);
        l2 += __shfl_xor(l2, off, 32);
#pragma unroll
        for (int h = 0; h < 3; ++h)
#pragma unroll
            for (int c = 0; c < 4; ++c) A[h][c] += __shfl_xor(A[h][c], off, 32);
    }
    __shared__ float so[8][18];
    if (k < 18) {                         // parallel epilogue: lane t computes channel t
        int tt = k;
        int h = tt / 6;
        float lh = (h == 0) ? l0 : (h == 1) ? l1 : l2;
        float Ah0 = (h == 0) ? A[0][0] : (h == 1) ? A[1][0] : A[2][0];
        float Ah1 = (h == 0) ? A[0][1] : (h == 1) ? A[1][1] : A[2][1];
        float Ah2 = (h == 0) ? A[0][2] : (h == 1) ? A[1][2] : A[2][2];
        float Ah3 = (h == 0) ? A[0][3] : (h == 1) ? A[1][3] : A[2][3];
        float acc = Ah0 * sM1[0][tt] + Ah1 * sM1[1][tt] + Ah2 * sM1[2][tt] + Ah3 * sM1[3][tt];
        float inv = 1.f / (lh * (float)KN);
        float x2v = fmaf(acc, inv, sc1[tt] * (1.f / (float)KN));
        out[(size_t)node * 18 + tt] = x2v;
        so[hw][tt] = x2v;
    }
    __syncthreads();
    if (threadIdx.x < 18) {
        int tt = threadIdx.x;
        float ps = 0.f, pss = 0.f;
#pragma unroll
        for (int h = 0; h < 8; ++h) { float vv = so[h][tt]; ps += vv; pss = fmaf(vv, vv, pss); }
        int slot = (blockIdx.x & (NSLOT - 1)) * 36;
        atomicAdd(&slots[slot + tt], ps);
        atomicAdd(&slots[slot + 18 + tt], pss);
    }
}

// ---------------- xe2 = [x0,S,x2raw] @ M2 + c2 ; pack fp16; inline prep2 ----------------
__global__ __launch_bounds__(256)
void xe2_kernel(const float* __restrict__ x0, const float4* __restrict__ S4,
                const float* __restrict__ x2,
                const float* __restrict__ SS, const float* __restrict__ X2S,
                const float* __restrict__ W0, const float* __restrict__ g1,
                const float* __restrict__ be1,
                const float* __restrict__ g2, const float* __restrict__ be2,
                const float* __restrict__ W2, const float* __restrict__ b2,
                const float* __restrict__ aW2,
                unsigned short* __restrict__ xeh) {
    __shared__ float muS[3], varS[3], alpha[18], beta[18], gam[18], del[18];
    __shared__ float sM2[22][18], sc2[18];
    int t = threadIdx.x;
    if (t < 3) {
        float s = 0.f, ss = 0.f;
#pragma unroll 8
        for (int i = 0; i < NSLOT; ++i) { s += SS[i * 8 + t]; ss += SS[i * 8 + 4 + t]; }
        float mu = s / (float)N_NODES;
        muS[t] = mu; varS[t] = ss / (float)N_NODES - mu * mu;
    }
    if (t < 18) {
        float s = 0.f, ss = 0.f;
#pragma unroll 8
        for (int i = 0; i < NSLOT; ++i) { s += X2S[i * 36 + t]; ss += X2S[i * 36 + 18 + t]; }
        float mu2 = s / (float)N_NODES;
        float var2 = ss / (float)N_NODES - mu2 * mu2;
        float g = rsqrtf(var2 + EPS) * g2[t];
        gam[t] = g; del[t] = be2[t] - mu2 * g;
    }
    __syncthreads();
    if (t < 18) {
        int h = t / 6;
        float w = W0[t] / (float)KN;
        float inv1 = rsqrtf(varS[h] * w * w + EPS);
        float gg = inv1 * g1[t];
        alpha[t] = w * gg;
        beta[t]  = be1[t] - w * gg * muS[h];
    }
    __syncthreads();
    if (t < 18) {
        int j = t;
        sM2[0][j] = W2[j];
        for (int h = 0; h < 3; ++h) {
            float acc = 0.f;
            for (int f = 0; f < 6; ++f) acc = fmaf(alpha[h * 6 + f], W2[(1 + h * 6 + f) * 18 + j], acc);
            sM2[1 + h][j] = acc;
        }
        for (int c = 0; c < 18; ++c) sM2[4 + c][j] = gam[c] * W2[(19 + c) * 18 + j];
        float cc = b2[j];
        for (int c = 0; c < 18; ++c) cc = fmaf(beta[c], W2[(1 + c) * 18 + j], cc);
        for (int c = 0; c < 18; ++c) cc = fmaf(del[c],  W2[(19 + c) * 18 + j], cc);
        sc2[j] = cc;
    }
    __syncthreads();
    int n = blockIdx.x * blockDim.x + threadIdx.x;
    if (n >= N_NODES) return;
    float xv = x0[n];
    float4 S = S4[n];
    float xr[18];
    const float2* x2p = (const float2*)(x2 + (size_t)n * 18);
#pragma unroll
    for (int q = 0; q < 9; ++q) { float2 v = x2p[q]; xr[2 * q] = v.x; xr[2 * q + 1] = v.y; }
    float row[18];
#pragma unroll
    for (int j = 0; j < 18; ++j) {
        float r = sc2[j];
        r = fmaf(xv,  sM2[0][j], r);
        r = fmaf(S.x, sM2[1][j], r);
        r = fmaf(S.y, sM2[2][j], r);
        r = fmaf(S.z, sM2[3][j], r);
#pragma unroll
        for (int c = 0; c < 18; ++c) r = fmaf(xr[c], sM2[4 + c][j], r);
        row[j] = r;
    }
    float q0 = 0.f, q1 = 0.f, q2 = 0.f;
#pragma unroll
    for (int f = 0; f < 6; ++f) {
        float a = aW2[6 + f];
        q0 = fmaf(row[f], a, q0);
        q1 = fmaf(row[6 + f], a, q1);
        q2 = fmaf(row[12 + f], a, q2);
    }
    union { unsigned short u[24]; uint4 v[3]; } pk;
#pragma unroll
    for (int j = 0; j < 18; ++j) pk.u[j] = __half_as_ushort(__float2half(row[j]));
    pk.u[18] = 0; pk.u[19] = 0;
    pk.u[20] = __half_as_ushort(__float2half(q0));
    pk.u[21] = __half_as_ushort(__float2half(q1));
    pk.u[22] = __half_as_ushort(__float2half(q2));
    pk.u[23] = 0;
    uint4* dst = (uint4*)(xeh + (size_t)n * 24);
    dst[0] = pk.v[0]; dst[1] = pk.v[1]; dst[2] = pk.v[2];
}

// ---------------- big attention (layer 2), fp16 gathers + fused channel stats ----------------
__global__ __launch_bounds__(256)
void att_big_kernel(const unsigned short* __restrict__ xeh,
                    const int* __restrict__ ei0, const int* __restrict__ ei1,
                    const float* __restrict__ aW, const float* __restrict__ abp,
                    float* __restrict__ out, float* __restrict__ slots) {
    int hw = threadIdx.x >> 5;
    int node = blockIdx.x * 8 + hw;          // grid exactly N/8
    int k = threadIdx.x & 31;
    int eidx = node * KN + k;
    int s = ei0[eidx], d = ei1[eidx];
    const unsigned short* rs = xeh + (size_t)s * 24;
    uint4 A = *(const uint4*)rs;                 // halves 0..7
    uint4 B = *(const uint4*)(rs + 8);           // halves 8..15
    unsigned int C = *(const unsigned int*)(rs + 16);  // halves 16,17
    uint2 Q = *(const uint2*)(xeh + (size_t)d * 24 + 20); // halves 20..23
    float2 p01 = h2f2(A.x), p23 = h2f2(A.y), p45 = h2f2(A.z), p67 = h2f2(A.w);
    float2 p89 = h2f2(B.x), pab = h2f2(B.y), pcd = h2f2(B.z), pef = h2f2(B.w);
    float2 pgh = h2f2(C);
    float2 q01 = h2f2(Q.x), q2_ = h2f2(Q.y);
    float r[18];
    r[0]=p01.x; r[1]=p01.y; r[2]=p23.x; r[3]=p23.y; r[4]=p45.x; r[5]=p45.y;
    r[6]=p67.x; r[7]=p67.y; r[8]=p89.x; r[9]=p89.y; r[10]=pab.x; r[11]=pab.y;
    r[12]=pcd.x; r[13]=pcd.y; r[14]=pef.x; r[15]=pef.y; r[16]=pgh.x; r[17]=pgh.y;
    float a0 = aW[0], a1 = aW[1], a2 = aW[2], a3 = aW[3], a4 = aW[4], a5 = aW[5];
    float ab = abp[0];
    float sc0 = fmaf(r[0],a0, fmaf(r[1],a1, fmaf(r[2],a2, fmaf(r[3],a3, fmaf(r[4],a4, r[5]*a5))))) + q01.x + ab;
    float sc1 = fmaf(r[6],a0, fmaf(r[7],a1, fmaf(r[8],a2, fmaf(r[9],a3, fmaf(r[10],a4, r[11]*a5))))) + q01.y + ab;
    float sc2 = fmaf(r[12],a0, fmaf(r[13],a1, fmaf(r[14],a2, fmaf(r[15],a3, fmaf(r[16],a4, r[17]*a5))))) + q2_.x + ab;
    float m0 = sc0, m1 = sc1, m2 = sc2;
#pragma unroll
    for (int off = 16; off > 0; off >>= 1) {
        m0 = fmaxf(m0, __shfl_xor(m0, off, 32));
        m1 = fmaxf(m1, __shfl_xor(m1, off, 32));
        m2 = fmaxf(m2, __shfl_xor(m2, off, 32));
    }
    float w0 = __expf(sc0 - m0), w1 = __expf(sc1 - m1), w2 = __expf(sc2 - m2);
    float l0 = w0, l1 = w1, l2 = w2;
    float v[18];
#pragma unroll
    for (int j = 0; j < 6; ++j) {
        v[j]      = w0 * r[j];
        v[6 + j]  = w1 * r[6 + j];
        v[12 + j] = w2 * r[12 + j];
    }
#pragma unroll
    for (int off = 16; off > 0; off >>= 1) {
        l0 += __shfl_xor(l0, off, 32);
        l1 += __shfl_xor(l1, off, 32);
        l2 += __shfl_xor(l2, off, 32);
#pragma unroll
        for (int j = 0; j < 18; ++j) v[j] += __shfl_xor(v[j], off, 32);
    }
    __shared__ float so[8][18];
    if (k == 0) {
        float i0 = 1.f / (l0 * (float)KN);
        float i1 = 1.f / (l1 * (float)KN);
        float i2 = 1.f / (l2 * (float)KN);
        size_t base = (size_t)node * 18;
#pragma unroll
        for (int j = 0; j < 6; ++j) {
            float o0 = v[j] * i0, o1 = v[6 + j] * i1, o2 = v[12 + j] * i2;
            out[base + j] = o0;      so[hw][j] = o0;
            out[base + 6 + j] = o1;  so[hw][6 + j] = o1;
            out[base + 12 + j] = o2; so[hw][12 + j] = o2;
        }
    }
    __syncthreads();
    if (threadIdx.x < 18) {
        int t = threadIdx.x;
        float ps = 0.f, pss = 0.f;
#pragma unroll
        for (int h = 0; h < 8; ++h) { float vv = so[h][t]; ps += vv; pss = fmaf(vv, vv, pss); }
        int slot = (blockIdx.x & (NSLOT - 1)) * 36;
        atomicAdd(&slots[slot + t], ps);
        atomicAdd(&slots[slot + 18 + t], pss);
    }
}

// ---------------- final: BN3 fold inline + y @ wf + cf ----------------
__global__ __launch_bounds__(256)
void final_kernel(const float4* __restrict__ y4, const float* __restrict__ YS,
                  const float* __restrict__ g3, const float* __restrict__ be3,
                  const float* __restrict__ fW, const float* __restrict__ fb,
                  float2* __restrict__ out2) {
    __shared__ float swf[18], part[18];
    __shared__ float scf;
    int t = threadIdx.x;
    if (t < 18) {
        float s = 0.f, ss = 0.f;
#pragma unroll 8
        for (int i = 0; i < NSLOT; ++i) { s += YS[i * 36 + t]; ss += YS[i * 36 + 18 + t]; }
        float mu = s / (float)N_NODES;
        float var = ss / (float)N_NODES - mu * mu;
        float g = rsqrtf(var + EPS) * g3[t];
        swf[t] = g * fW[t];
        part[t] = (be3[t] - mu * g) * fW[t];
    }
    __syncthreads();
    if (t == 0) {
        float cf = fb[0];
        for (int j = 0; j < 18; ++j) cf += part[j];
        scf = cf;
    }
    __syncthreads();
    int i = blockIdx.x * blockDim.x + threadIdx.x;
    if (i >= 50000) return;
    const float4* yp = y4 + (size_t)i * 9;
    float a[36];
#pragma unroll
    for (int q = 0; q < 9; ++q) {
        float4 v = yp[q];
        a[4 * q] = v.x; a[4 * q + 1] = v.y; a[4 * q + 2] = v.z; a[4 * q + 3] = v.w;
    }
    float acc0 = scf, acc1 = scf;
#pragma unroll
    for (int j = 0; j < 18; ++j) {
        float w = swf[j];
        acc0 = fmaf(a[j], w, acc0);
        acc1 = fmaf(a[18 + j], w, acc1);
    }
    out2[i] = make_float2(acc0, acc1);
}

extern "C" void kernel_launch(void* const* d_in, const int* in_sizes, int n_in,
                              void* d_out, int out_size, void* d_ws, size_t ws_size,
                              hipStream_t stream) {
    const float* x   = (const float*)d_in[0];
    const int*   ei  = (const int*)d_in[1];
    const float* e   = (const float*)d_in[2];
    const float* W0  = (const float*)d_in[3];
    const float* b0  = (const float*)d_in[4];
    const float* aW0 = (const float*)d_in[5];
    const float* ab0 = (const float*)d_in[6];
    const float* W1  = (const float*)d_in[7];
    const float* b1  = (const float*)d_in[8];
    const float* aW1 = (const float*)d_in[9];
    const float* ab1 = (const float*)d_in[10];
    const float* W2  = (const float*)d_in[11];
    const float* b2  = (const float*)d_in[12];
    const float* aW2 = (const float*)d_in[13];
    const float* ab2 = (const float*)d_in[14];
    const float* g0  = (const float*)d_in[15];
    const float* be0 = (const float*)d_in[16];
    const float* g1  = (const float*)d_in[17];
    const float* be1 = (const float*)d_in[18];
    const float* g2  = (const float*)d_in[19];
    const float* be2 = (const float*)d_in[20];
    const float* g3  = (const float*)d_in[21];
    const float* be3 = (const float*)d_in[22];
    const float* fW  = (const float*)d_in[23];
    const float* fb  = (const float*)d_in[24];

    const int* ei0 = ei;
    const int* ei1 = ei + (size_t)N_NODES * KN;

    float*  ws  = (float*)d_ws;
    float*  x0  = ws + OFF_X0;
    unsigned short* xeh = (unsigned short*)(ws + OFF_XEH);
    uint4*  z1q1 = (uint4*)(ws + OFF_Z1Q);
    float4* S4  = (float4*)(ws + OFF_S4);
    float*  x2  = ws + OFF_X2;
    float*  y   = ws + OFF_Y;
    float*  TX  = ws + OFF_TX;
    float*  SS  = ws + OFF_SS;
    float*  X2S = ws + OFF_X2S;
    float*  YS  = ws + OFF_YS;

    // zero all stats accumulators
    hipMemsetAsync(TX, 0, (OFF_END - OFF_TX) * sizeof(float), stream);

    // stage 0: BN0
    statsx_kernel<<<98, 256, 0, stream>>>((const float4*)x, TX);
    x0_kernel<<<98, 256, 0, stream>>>((const float4*)x, TX, g0, be0, (float4*)x0);

    // layer 0 (rank-1): S per node, fused S stats
    att0_kernel<<<N_NODES / 8, 256, 0, stream>>>(x0, ei0, ei1, (const float2*)e,
                                                 W0, b0, aW0, ab0, S4, SS);

    // layer 1 (z-record scheme, inline prep1)
    zq1_kernel<<<(N_NODES + 255) / 256, 256, 0, stream>>>(x0, S4, SS, W0, g1, be1, W1, b1, aW1, z1q1);
    att_z1_kernel<<<N_NODES / 8, 256, 0, stream>>>(z1q1, ei0, ei1, SS, W0, g1, be1, W1, b1,
                                                   aW1, ab1, x2, X2S);

    // layer 2 (inline prep2)
    xe2_kernel<<<(N_NODES + 255) / 256, 256, 0, stream>>>(x0, S4, x2, SS, X2S,
                                                          W0, g1, be1, g2, be2, W2, b2, aW2, xeh);
    att_big_kernel<<<N_NODES / 8, 256, 0, stream>>>(xeh, ei0, ei1, aW2, ab2, y, YS);

    // final BN3 + fc (inline prepF)
    final_kernel<<<(50000 + 255) / 256, 256, 0, stream>>>((const float4*)y, YS, g3, be3, fW, fb,
                                                          (float2*)d_out);
}

// Round 13
// 299.004 us; speedup vs baseline: 1.1109x; 1.1109x over previous
//
#include <hip/hip_runtime.h>
#include <hip/hip_fp16.h>

#define N_NODES 100000
#define KN 32
#define EPS 1e-5f
#define NSLOT 128

// ---------------- workspace layout (float offsets) ----------------
#define OFF_X0   0          // [100000]   normalized scalar input
#define OFF_XEH  500000     // [100000*24 ushorts] packed fp16 xe2 rows: 18 xe, 2 pad, 3 q, pad
#define OFF_Z1Q  1800000    // [100000*8 ushorts] layer1 records: x0,S0,S1,S2,q0,q1,q2,pad
#define OFF_S4   2500000    // [100000*4] layer0 per-head weighted sums (float4)
#define OFF_X2   2900000    // [100000*18] layer1 raw output (fp32)
#define OFF_Y    4700000    // [100000*18] layer2 raw output (fp32)
#define OFF_TX   6500000    // [16]   x sum/ss
#define OFF_SS   6500016    // [128*8]  S slotted stats
#define OFF_X2S  6501040    // [128*36] x2 slotted stats
#define OFF_YS   6505648    // [128*36] y slotted stats
#define OFF_P    6510256    // [1024] derived params
// P: 0 s0, 1 t0 | 2..4 A | 5..7 B | 8..10 C | 11 ew0, 12 ew1
//    16..87 M1(4x18), 88..105 c1 | 112..507 M2(22x18), 508..525 c2
//    528..545 wf, 546 cf | 548..559 PM1(4x3), 560..562 pc1

__device__ inline float2 h2f2(unsigned int w) {
    __half2 h = *reinterpret_cast<__half2*>(&w);
    return __half22float2(h);
}
__device__ inline unsigned int f2h2u(float a) {
    __half2 h = __float2half2_rn(a);
    return *reinterpret_cast<unsigned int*>(&h);
}
__device__ inline unsigned int hmul2u(unsigned int a, unsigned int b) {
    __half2 r = __hmul2(*reinterpret_cast<__half2*>(&a), *reinterpret_cast<__half2*>(&b));
    return *reinterpret_cast<unsigned int*>(&r);
}
__device__ inline unsigned int hadd2u(unsigned int a, unsigned int b) {
    __half2 r = __hadd2(*reinterpret_cast<__half2*>(&a), *reinterpret_cast<__half2*>(&b));
    return *reinterpret_cast<unsigned int*>(&r);
}

// ---------------- stats of scalar input x (vectorized) ----------------
__global__ __launch_bounds__(256)
void statsx_kernel(const float4* __restrict__ x4, float* __restrict__ acc) {
    int i = blockIdx.x * 256 + threadIdx.x;
    float s = 0.f, ss = 0.f;
    if (i < 25000) {
        float4 v = x4[i];
        s = v.x + v.y + v.z + v.w;
        ss = v.x * v.x + v.y * v.y + v.z * v.z + v.w * v.w;
    }
#pragma unroll
    for (int off = 32; off > 0; off >>= 1) {
        s  += __shfl_xor(s,  off, 64);
        ss += __shfl_xor(ss, off, 64);
    }
    __shared__ float ls[4], lss[4];
    int wid = threadIdx.x >> 6;
    if ((threadIdx.x & 63) == 0) { ls[wid] = s; lss[wid] = ss; }
    __syncthreads();
    if (threadIdx.x == 0) {
        atomicAdd(&acc[0], ls[0] + ls[1] + ls[2] + ls[3]);
        atomicAdd(&acc[1], lss[0] + lss[1] + lss[2] + lss[3]);
    }
}

// ---------------- prep0: BN0 fold + layer0 score constants ----------------
__global__ void prep0_kernel(const float* __restrict__ T, float* __restrict__ P,
                             const float* g0, const float* be0,
                             const float* W0, const float* b0,
                             const float* aW0, const float* ab0) {
    if (threadIdx.x || blockIdx.x) return;
    float mu  = T[0] / (float)N_NODES;
    float var = T[1] / (float)N_NODES - mu * mu;
    float inv = rsqrtf(var + EPS);
    float s0 = inv * g0[0];
    P[0] = s0; P[1] = be0[0] - mu * s0;
    for (int h = 0; h < 3; ++h) {
        float A = 0.f, B = 0.f, Cc = 0.f;
        for (int f = 0; f < 6; ++f) {
            A  = fmaf(W0[h * 6 + f], aW0[f], A);
            B  = fmaf(W0[h * 6 + f], aW0[6 + f], B);
            Cc = fmaf(b0[h * 6 + f], aW0[f] + aW0[6 + f], Cc);
        }
        P[2 + h] = A; P[5 + h] = B; P[8 + h] = Cc + ab0[0];
    }
    P[11] = aW0[12]; P[12] = aW0[13];
}

// ---------------- x0 = BN0(x), vectorized ----------------
__global__ void x0_kernel(const float4* __restrict__ x4, const float* __restrict__ P,
                          float4* __restrict__ x0) {
    int i = blockIdx.x * blockDim.x + threadIdx.x;
    if (i < 25000) {
        float4 v = x4[i];
        float s = P[0], t = P[1];
        x0[i] = make_float4(fmaf(v.x, s, t), fmaf(v.y, s, t), fmaf(v.z, s, t), fmaf(v.w, s, t));
    }
}

// ---------------- layer0 attention + fused S stats ----------------
__global__ __launch_bounds__(256)
void att0_kernel(const float* __restrict__ x0,
                 const int* __restrict__ ei0, const int* __restrict__ ei1,
                 const float2* __restrict__ e2,
                 const float* __restrict__ P, float4* __restrict__ S4,
                 float* __restrict__ SS) {
    int hw = threadIdx.x >> 5;
    int node = blockIdx.x * 8 + hw;          // grid exactly N/8
    int k = threadIdx.x & 31;
    int eidx = node * KN + k;
    int s = ei0[eidx], d = ei1[eidx];
    float xs = x0[s], xd = x0[d];
    float2 ef = e2[eidx];
    float eb = fmaf(ef.x, P[11], ef.y * P[12]);
    float sc0 = fmaf(xs, P[2], fmaf(xd, P[5], P[8]  + eb));
    float sc1 = fmaf(xs, P[3], fmaf(xd, P[6], P[9]  + eb));
    float sc2 = fmaf(xs, P[4], fmaf(xd, P[7], P[10] + eb));
    float m0 = sc0, m1 = sc1, m2 = sc2;
#pragma unroll
    for (int off = 16; off > 0; off >>= 1) {
        m0 = fmaxf(m0, __shfl_xor(m0, off, 32));
        m1 = fmaxf(m1, __shfl_xor(m1, off, 32));
        m2 = fmaxf(m2, __shfl_xor(m2, off, 32));
    }
    float w0 = __expf(sc0 - m0), w1 = __expf(sc1 - m1), w2 = __expf(sc2 - m2);
    float l0 = w0, l1 = w1, l2 = w2;
    float a0 = w0 * xs, a1 = w1 * xs, a2 = w2 * xs;
#pragma unroll
    for (int off = 16; off > 0; off >>= 1) {
        l0 += __shfl_xor(l0, off, 32); a0 += __shfl_xor(a0, off, 32);
        l1 += __shfl_xor(l1, off, 32); a1 += __shfl_xor(a1, off, 32);
        l2 += __shfl_xor(l2, off, 32); a2 += __shfl_xor(a2, off, 32);
    }
    __shared__ float sS[8][4];
    if (k == 0) {
        float v0 = a0 / l0, v1 = a1 / l1, v2 = a2 / l2;
        S4[node] = make_float4(v0, v1, v2, 0.f);
        sS[hw][0] = v0; sS[hw][1] = v1; sS[hw][2] = v2;
    }
    __syncthreads();
    if (threadIdx.x < 3) {
        float ps = 0.f, pss = 0.f;
#pragma unroll
        for (int h = 0; h < 8; ++h) { float v = sS[h][threadIdx.x]; ps += v; pss = fmaf(v, v, pss); }
        int slot = (blockIdx.x & (NSLOT - 1)) * 8;
        atomicAdd(&SS[slot + threadIdx.x], ps);
        atomicAdd(&SS[slot + 4 + threadIdx.x], pss);
    }
}

// ---------------- prep1: reduce S slots, fold BN1 into M1 (4x18)+c1, PM1/pc1 ----------------
__global__ void prep1_kernel(const float* __restrict__ SS, float* __restrict__ P,
                             const float* W0, const float* g1, const float* be1,
                             const float* W1, const float* b1,
                             const float* aW1, const float* ab1) {
    __shared__ float muS[3], varS[3], alpha[18], beta[18], sM1[4][18], sc1[18];
    int t = threadIdx.x;
    if (t < 3) {
        float s = 0.f, ss = 0.f;
#pragma unroll 8
        for (int i = 0; i < NSLOT; ++i) { s += SS[i * 8 + t]; ss += SS[i * 8 + 4 + t]; }
        float mu = s / (float)N_NODES;
        muS[t] = mu; varS[t] = ss / (float)N_NODES - mu * mu;
    }
    __syncthreads();
    if (t < 18) {
        int h = t / 6;
        float w = W0[t] / (float)KN;
        float inv1 = rsqrtf(varS[h] * w * w + EPS);
        float gg = inv1 * g1[t];
        alpha[t] = w * gg;
        beta[t]  = be1[t] - w * gg * muS[h];
    }
    __syncthreads();
    if (t < 18) {
        int j = t;
        float* M1 = P + 16; float* c1 = P + 88;
        float m0 = W1[j];
        sM1[0][j] = m0; M1[j] = m0;
        for (int h = 0; h < 3; ++h) {
            float acc = 0.f;
            for (int f = 0; f < 6; ++f) acc = fmaf(alpha[h * 6 + f], W1[(1 + h * 6 + f) * 18 + j], acc);
            sM1[1 + h][j] = acc; M1[(1 + h) * 18 + j] = acc;
        }
        float cc = b1[j];
        for (int c = 0; c < 18; ++c) cc = fmaf(beta[c], W1[(1 + c) * 18 + j], cc);
        sc1[j] = cc; c1[j] = cc;
    }
    __syncthreads();
    if (t < 12) {                       // PM1[c][h] = sum_f M1[c][h*6+f]*aW1[f]
        int c = t / 3, h = t - c * 3;
        float acc = 0.f;
        for (int f = 0; f < 6; ++f) acc = fmaf(sM1[c][h * 6 + f], aW1[f], acc);
        P[548 + c * 3 + h] = acc;
    } else if (t < 15) {                // pc1[h] = sum_f c1[h*6+f]*aW1[f] + ab1
        int h = t - 12;
        float acc = ab1[0];
        for (int f = 0; f < 6; ++f) acc = fmaf(sc1[h * 6 + f], aW1[f], acc);
        P[560 + h] = acc;
    }
}

// ---------------- zq1: per node, pack [x0,S0,S1,S2,q0,q1,q2,pad] fp16 (16B) ----------------
__global__ void zq1_kernel(const float* __restrict__ x0, const float4* __restrict__ S4,
                           const float* __restrict__ P, const float* __restrict__ aW1,
                           uint4* __restrict__ z1q1) {
    int n = blockIdx.x * blockDim.x + threadIdx.x;
    if (n >= N_NODES) return;
    float xv = x0[n];
    float4 S = S4[n];
    const float* M1 = P + 16; const float* c1 = P + 88;
    float row[18];
#pragma unroll
    for (int j = 0; j < 18; ++j) {
        float r = c1[j];
        r = fmaf(xv,  M1[j],      r);
        r = fmaf(S.x, M1[18 + j], r);
        r = fmaf(S.y, M1[36 + j], r);
        r = fmaf(S.z, M1[54 + j], r);
        row[j] = r;
    }
    float q0 = 0.f, q1 = 0.f, q2 = 0.f;
#pragma unroll
    for (int f = 0; f < 6; ++f) {
        float a = aW1[6 + f];
        q0 = fmaf(row[f], a, q0);
        q1 = fmaf(row[6 + f], a, q1);
        q2 = fmaf(row[12 + f], a, q2);
    }
    union { unsigned short u[8]; uint4 v; } pk;
    pk.u[0] = __half_as_ushort(__float2half(xv));
    pk.u[1] = __half_as_ushort(__float2half(S.x));
    pk.u[2] = __half_as_ushort(__float2half(S.y));
    pk.u[3] = __half_as_ushort(__float2half(S.z));
    pk.u[4] = __half_as_ushort(__float2half(q0));
    pk.u[5] = __half_as_ushort(__float2half(q1));
    pk.u[6] = __half_as_ushort(__float2half(q2));
    pk.u[7] = 0;
    z1q1[n] = pk.v;
}

// ---------------- layer1 attention on z-records: packed-fp16 butterfly ----------------
__global__ __launch_bounds__(256)
void att_z1_kernel(const uint4* __restrict__ z1q1,
                   const int* __restrict__ ei0, const int* __restrict__ ei1,
                   const float* __restrict__ P,
                   float* __restrict__ out, float* __restrict__ slots) {
    int hw = threadIdx.x >> 5;
    int node = blockIdx.x * 8 + hw;          // grid exactly N/8
    int k = threadIdx.x & 31;
    int eidx = node * KN + k;
    int s = ei0[eidx], d = ei1[eidx];
    uint4 Rs = z1q1[s];
    uint4 Rd = z1q1[d];
    float2 z01 = h2f2(Rs.x), z23 = h2f2(Rs.y);
    float zc0 = z01.x, zc1 = z01.y, zc2 = z23.x, zc3 = z23.y;
    float2 q01 = h2f2(Rd.z), q23 = h2f2(Rd.w);
    const float* PM = P + 548;   // PM[c*3+h]
    const float* pc = P + 560;
    float sc0 = pc[0] + q01.x, sc1 = pc[1] + q01.y, sc2 = pc[2] + q23.x;
    sc0 = fmaf(zc0, PM[0], fmaf(zc1, PM[3], fmaf(zc2, PM[6], fmaf(zc3, PM[9],  sc0))));
    sc1 = fmaf(zc0, PM[1], fmaf(zc1, PM[4], fmaf(zc2, PM[7], fmaf(zc3, PM[10], sc1))));
    sc2 = fmaf(zc0, PM[2], fmaf(zc1, PM[5], fmaf(zc2, PM[8], fmaf(zc3, PM[11], sc2))));
    float m0 = sc0, m1 = sc1, m2 = sc2;
#pragma unroll
    for (int off = 16; off > 0; off >>= 1) {
        m0 = fmaxf(m0, __shfl_xor(m0, off, 32));
        m1 = fmaxf(m1, __shfl_xor(m1, off, 32));
        m2 = fmaxf(m2, __shfl_xor(m2, off, 32));
    }
    float w0 = __expf(sc0 - m0), w1 = __expf(sc1 - m1), w2 = __expf(sc2 - m2);
    float l0 = w0, l1 = w1, l2 = w2;
    // packed A accumulation: Ahu[h][0]=(c0,c1), Ahu[h][1]=(c2,c3) as half2
    unsigned int wh0 = f2h2u(w0), wh1 = f2h2u(w1), wh2 = f2h2u(w2);
    unsigned int A00 = hmul2u(Rs.x, wh0), A01 = hmul2u(Rs.y, wh0);
    unsigned int A10 = hmul2u(Rs.x, wh1), A11 = hmul2u(Rs.y, wh1);
    unsigned int A20 = hmul2u(Rs.x, wh2), A21 = hmul2u(Rs.y, wh2);
#pragma unroll
    for (int off = 16; off > 0; off >>= 1) {
        l0 += __shfl_xor(l0, off, 32);
        l1 += __shfl_xor(l1, off, 32);
        l2 += __shfl_xor(l2, off, 32);
        A00 = hadd2u(A00, __shfl_xor(A00, off, 32));
        A01 = hadd2u(A01, __shfl_xor(A01, off, 32));
        A10 = hadd2u(A10, __shfl_xor(A10, off, 32));
        A11 = hadd2u(A11, __shfl_xor(A11, off, 32));
        A20 = hadd2u(A20, __shfl_xor(A20, off, 32));
        A21 = hadd2u(A21, __shfl_xor(A21, off, 32));
    }
    __shared__ float so[8][18];
    if (k < 18) {                         // parallel epilogue: lane t computes channel t
        int tt = k;
        int h = tt / 6;
        float lh = (h == 0) ? l0 : (h == 1) ? l1 : l2;
        unsigned int Au0 = (h == 0) ? A00 : (h == 1) ? A10 : A20;
        unsigned int Au1 = (h == 0) ? A01 : (h == 1) ? A11 : A21;
        float2 a01 = h2f2(Au0), a23 = h2f2(Au1);
        const float* M1 = P + 16; const float* c1 = P + 88;
        float acc = a01.x * M1[tt] + a01.y * M1[18 + tt] + a23.x * M1[36 + tt] + a23.y * M1[54 + tt];
        float inv = 1.f / (lh * (float)KN);
        float x2v = fmaf(acc, inv, c1[tt] * (1.f / (float)KN));
        out[(size_t)node * 18 + tt] = x2v;
        so[hw][tt] = x2v;
    }
    __syncthreads();
    if (threadIdx.x < 18) {
        int tt = threadIdx.x;
        float ps = 0.f, pss = 0.f;
#pragma unroll
        for (int h = 0; h < 8; ++h) { float vv = so[h][tt]; ps += vv; pss = fmaf(vv, vv, pss); }
        int slot = (blockIdx.x & (NSLOT - 1)) * 36;
        atomicAdd(&slots[slot + tt], ps);
        atomicAdd(&slots[slot + 18 + tt], pss);
    }
}

// ---------------- prep2: reduce slots, fold BN1+BN2 into M2 (22x18) + c2 ----------------
__global__ void prep2_kernel(const float* __restrict__ SS, const float* __restrict__ X2S,
                             float* __restrict__ P,
                             const float* W0, const float* g1, const float* be1,
                             const float* g2, const float* be2,
                             const float* W2, const float* b2) {
    __shared__ float muS[3], varS[3], alpha[18], beta[18], gam[18], del[18];
    int t = threadIdx.x;
    if (t < 3) {
        float s = 0.f, ss = 0.f;
#pragma unroll 8
        for (int i = 0; i < NSLOT; ++i) { s += SS[i * 8 + t]; ss += SS[i * 8 + 4 + t]; }
        float mu = s / (float)N_NODES;
        muS[t] = mu; varS[t] = ss / (float)N_NODES - mu * mu;
    }
    if (t < 18) {
        float s = 0.f, ss = 0.f;
#pragma unroll 8
        for (int i = 0; i < NSLOT; ++i) { s += X2S[i * 36 + t]; ss += X2S[i * 36 + 18 + t]; }
        float mu2 = s / (float)N_NODES;
        float var2 = ss / (float)N_NODES - mu2 * mu2;
        float g = rsqrtf(var2 + EPS) * g2[t];
        gam[t] = g; del[t] = be2[t] - mu2 * g;
    }
    __syncthreads();
    if (t < 18) {
        int h = t / 6;
        float w = W0[t] / (float)KN;
        float inv1 = rsqrtf(varS[h] * w * w + EPS);
        float gg = inv1 * g1[t];
        alpha[t] = w * gg;
        beta[t]  = be1[t] - w * gg * muS[h];
    }
    __syncthreads();
    if (t < 18) {
        int j = t;
        float* M2 = P + 112; float* c2 = P + 508;
        M2[j] = W2[j];
        for (int h = 0; h < 3; ++h) {
            float acc = 0.f;
            for (int f = 0; f < 6; ++f) acc = fmaf(alpha[h * 6 + f], W2[(1 + h * 6 + f) * 18 + j], acc);
            M2[(1 + h) * 18 + j] = acc;
        }
        for (int c = 0; c < 18; ++c) M2[(4 + c) * 18 + j] = gam[c] * W2[(19 + c) * 18 + j];
        float cc = b2[j];
        for (int c = 0; c < 18; ++c) cc = fmaf(beta[c], W2[(1 + c) * 18 + j], cc);
        for (int c = 0; c < 18; ++c) cc = fmaf(del[c],  W2[(19 + c) * 18 + j], cc);
        c2[j] = cc;
    }
}

// ---------------- pack row[18] + q[3] into 24 fp16 (48B) ----------------
__device__ inline void pack_row(unsigned short* __restrict__ xeh, int n,
                                const float* row, float q0, float q1, float q2) {
    union { unsigned short u[24]; uint4 v[3]; } pk;
#pragma unroll
    for (int j = 0; j < 18; ++j) pk.u[j] = __half_as_ushort(__float2half(row[j]));
    pk.u[18] = 0; pk.u[19] = 0;
    pk.u[20] = __half_as_ushort(__float2half(q0));
    pk.u[21] = __half_as_ushort(__float2half(q1));
    pk.u[22] = __half_as_ushort(__float2half(q2));
    pk.u[23] = 0;
    uint4* dst = (uint4*)(xeh + (size_t)n * 24);
    dst[0] = pk.v[0]; dst[1] = pk.v[1]; dst[2] = pk.v[2];
}

// ---------------- xe2 = [x0,S,x2raw] @ M2 + c2 ; pack fp16 row+q ----------------
__global__ void xe2_kernel(const float* __restrict__ x0, const float4* __restrict__ S4,
                           const float* __restrict__ x2, const float* __restrict__ P,
                           const float* __restrict__ aW2,
                           unsigned short* __restrict__ xeh) {
    int n = blockIdx.x * blockDim.x + threadIdx.x;
    if (n >= N_NODES) return;
    float xv = x0[n];
    float4 S = S4[n];
    float xr[18];
    const float2* x2p = (const float2*)(x2 + (size_t)n * 18);
#pragma unroll
    for (int q = 0; q < 9; ++q) { float2 v = x2p[q]; xr[2 * q] = v.x; xr[2 * q + 1] = v.y; }
    const float* M2 = P + 112; const float* c2 = P + 508;
    float row[18];
#pragma unroll
    for (int j = 0; j < 18; ++j) {
        float r = c2[j];
        r = fmaf(xv,  M2[j],      r);
        r = fmaf(S.x, M2[18 + j], r);
        r = fmaf(S.y, M2[36 + j], r);
        r = fmaf(S.z, M2[54 + j], r);
#pragma unroll
        for (int c = 0; c < 18; ++c) r = fmaf(xr[c], M2[(4 + c) * 18 + j], r);
        row[j] = r;
    }
    float q0 = 0.f, q1 = 0.f, q2 = 0.f;
#pragma unroll
    for (int f = 0; f < 6; ++f) {
        float a = aW2[6 + f];
        q0 = fmaf(row[f], a, q0);
        q1 = fmaf(row[6 + f], a, q1);
        q2 = fmaf(row[12 + f], a, q2);
    }
    pack_row(xeh, n, row, q0, q1, q2);
}

// ---------------- big attention (layer 2): packed-fp16 butterfly ----------------
__global__ __launch_bounds__(256)
void att_big_kernel(const unsigned short* __restrict__ xeh,
                    const int* __restrict__ ei0, const int* __restrict__ ei1,
                    const float* __restrict__ aW, const float* __restrict__ abp,
                    float* __restrict__ out, float* __restrict__ slots) {
    int hw = threadIdx.x >> 5;
    int node = blockIdx.x * 8 + hw;          // grid exactly N/8
    int k = threadIdx.x & 31;
    int eidx = node * KN + k;
    int s = ei0[eidx], d = ei1[eidx];
    const unsigned short* rs = xeh + (size_t)s * 24;
    uint4 A = *(const uint4*)rs;                 // halves 0..7
    uint4 B = *(const uint4*)(rs + 8);           // halves 8..15
    unsigned int C = *(const unsigned int*)(rs + 16);  // halves 16,17
    uint2 Q = *(const uint2*)(xeh + (size_t)d * 24 + 20); // halves 20..23
    float2 p01 = h2f2(A.x), p23 = h2f2(A.y), p45 = h2f2(A.z), p67 = h2f2(A.w);
    float2 p89 = h2f2(B.x), pab = h2f2(B.y), pcd = h2f2(B.z), pef = h2f2(B.w);
    float2 pgh = h2f2(C);
    float2 q01 = h2f2(Q.x), q2_ = h2f2(Q.y);
    float a0 = aW[0], a1 = aW[1], a2 = aW[2], a3 = aW[3], a4 = aW[4], a5 = aW[5];
    float ab = abp[0];
    float sc0 = fmaf(p01.x,a0, fmaf(p01.y,a1, fmaf(p23.x,a2, fmaf(p23.y,a3, fmaf(p45.x,a4, p45.y*a5))))) + q01.x + ab;
    float sc1 = fmaf(p67.x,a0, fmaf(p67.y,a1, fmaf(p89.x,a2, fmaf(p89.y,a3, fmaf(pab.x,a4, pab.y*a5))))) + q01.y + ab;
    float sc2 = fmaf(pcd.x,a0, fmaf(pcd.y,a1, fmaf(pef.x,a2, fmaf(pef.y,a3, fmaf(pgh.x,a4, pgh.y*a5))))) + q2_.x + ab;
    float m0 = sc0, m1 = sc1, m2 = sc2;
#pragma unroll
    for (int off = 16; off > 0; off >>= 1) {
        m0 = fmaxf(m0, __shfl_xor(m0, off, 32));
        m1 = fmaxf(m1, __shfl_xor(m1, off, 32));
        m2 = fmaxf(m2, __shfl_xor(m2, off, 32));
    }
    float w0 = __expf(sc0 - m0), w1 = __expf(sc1 - m1), w2 = __expf(sc2 - m2);
    float l0 = w0, l1 = w1, l2 = w2;
    // packed v accumulation: 9 half2 words, pair p = channels (2p, 2p+1)
    unsigned int wh0 = f2h2u(w0), wh1 = f2h2u(w1), wh2 = f2h2u(w2);
    unsigned int v0 = hmul2u(A.x, wh0), v1 = hmul2u(A.y, wh0), v2 = hmul2u(A.z, wh0);
    unsigned int v3 = hmul2u(A.w, wh1), v4 = hmul2u(B.x, wh1), v5 = hmul2u(B.y, wh1);
    unsigned int v6 = hmul2u(B.z, wh2), v7 = hmul2u(B.w, wh2), v8 = hmul2u(C,   wh2);
#pragma unroll
    for (int off = 16; off > 0; off >>= 1) {
        l0 += __shfl_xor(l0, off, 32);
        l1 += __shfl_xor(l1, off, 32);
        l2 += __shfl_xor(l2, off, 32);
        v0 = hadd2u(v0, __shfl_xor(v0, off, 32));
        v1 = hadd2u(v1, __shfl_xor(v1, off, 32));
        v2 = hadd2u(v2, __shfl_xor(v2, off, 32));
        v3 = hadd2u(v3, __shfl_xor(v3, off, 32));
        v4 = hadd2u(v4, __shfl_xor(v4, off, 32));
        v5 = hadd2u(v5, __shfl_xor(v5, off, 32));
        v6 = hadd2u(v6, __shfl_xor(v6, off, 32));
        v7 = hadd2u(v7, __shfl_xor(v7, off, 32));
        v8 = hadd2u(v8, __shfl_xor(v8, off, 32));
    }
    __shared__ float so[8][18];
    if (k == 0) {
        float v[18];
        float2 t0;
        t0 = h2f2(v0); v[0]  = t0.x; v[1]  = t0.y;
        t0 = h2f2(v1); v[2]  = t0.x; v[3]  = t0.y;
        t0 = h2f2(v2); v[4]  = t0.x; v[5]  = t0.y;
        t0 = h2f2(v3); v[6]  = t0.x; v[7]  = t0.y;
        t0 = h2f2(v4); v[8]  = t0.x; v[9]  = t0.y;
        t0 = h2f2(v5); v[10] = t0.x; v[11] = t0.y;
        t0 = h2f2(v6); v[12] = t0.x; v[13] = t0.y;
        t0 = h2f2(v7); v[14] = t0.x; v[15] = t0.y;
        t0 = h2f2(v8); v[16] = t0.x; v[17] = t0.y;
        float i0 = 1.f / (l0 * (float)KN);
        float i1 = 1.f / (l1 * (float)KN);
        float i2 = 1.f / (l2 * (float)KN);
        size_t base = (size_t)node * 18;
#pragma unroll
        for (int j = 0; j < 6; ++j) {
            float o0 = v[j] * i0, o1 = v[6 + j] * i1, o2 = v[12 + j] * i2;
            out[base + j] = o0;      so[hw][j] = o0;
            out[base + 6 + j] = o1;  so[hw][6 + j] = o1;
            out[base + 12 + j] = o2; so[hw][12 + j] = o2;
        }
    }
    __syncthreads();
    if (threadIdx.x < 18) {
        int t = threadIdx.x;
        float ps = 0.f, pss = 0.f;
#pragma unroll
        for (int h = 0; h < 8; ++h) { float vv = so[h][t]; ps += vv; pss = fmaf(vv, vv, pss); }
        int slot = (blockIdx.x & (NSLOT - 1)) * 36;
        atomicAdd(&slots[slot + t], ps);
        atomicAdd(&slots[slot + 18 + t], pss);
    }
}

// ---------------- prepF: reduce Y slots, fold BN3 into final dot ----------------
__global__ void prepF_kernel(const float* __restrict__ YS, float* __restrict__ P,
                             const float* g3, const float* be3,
                             const float* fW, const float* fb) {
    __shared__ float part[18];
    int t = threadIdx.x;
    if (t < 18) {
        float s = 0.f, ss = 0.f;
#pragma unroll 8
        for (int i = 0; i < NSLOT; ++i) { s += YS[i * 36 + t]; ss += YS[i * 36 + 18 + t]; }
        float mu = s / (float)N_NODES;
        float var = ss / (float)N_NODES - mu * mu;
        float g = rsqrtf(var + EPS) * g3[t];
        P[528 + t] = g * fW[t];
        part[t] = (be3[t] - mu * g) * fW[t];
    }
    __syncthreads();
    if (t == 0) {
        float cf = fb[0];
        for (int j = 0; j < 18; ++j) cf += part[j];
        P[546] = cf;
    }
}

// ---------------- final: out = y @ wf + cf (2 nodes/thread, float4 loads) ----------------
__global__ __launch_bounds__(256)
void final_kernel(const float4* __restrict__ y4, const float* __restrict__ P,
                  float2* __restrict__ out2) {
    int i = blockIdx.x * blockDim.x + threadIdx.x;
    if (i >= 50000) return;
    const float4* yp = y4 + (size_t)i * 9;
    float a[36];
#pragma unroll
    for (int q = 0; q < 9; ++q) {
        float4 v = yp[q];
        a[4 * q] = v.x; a[4 * q + 1] = v.y; a[4 * q + 2] = v.z; a[4 * q + 3] = v.w;
    }
    float cf = P[546];
    float acc0 = cf, acc1 = cf;
#pragma unroll
    for (int j = 0; j < 18; ++j) {
        float w = P[528 + j];
        acc0 = fmaf(a[j], w, acc0);
        acc1 = fmaf(a[18 + j], w, acc1);
    }
    out2[i] = make_float2(acc0, acc1);
}

extern "C" void kernel_launch(void* const* d_in, const int* in_sizes, int n_in,
                              void* d_out, int out_size, void* d_ws, size_t ws_size,
                              hipStream_t stream) {
    const float* x   = (const float*)d_in[0];
    const int*   ei  = (const int*)d_in[1];
    const float* e   = (const float*)d_in[2];
    const float* W0  = (const float*)d_in[3];
    const float* b0  = (const float*)d_in[4];
    const float* aW0 = (const float*)d_in[5];
    const float* ab0 = (const float*)d_in[6];
    const float* W1  = (const float*)d_in[7];
    const float* b1  = (const float*)d_in[8];
    const float* aW1 = (const float*)d_in[9];
    const float* ab1 = (const float*)d_in[10];
    const float* W2  = (const float*)d_in[11];
    const float* b2  = (const float*)d_in[12];
    const float* aW2 = (const float*)d_in[13];
    const float* ab2 = (const float*)d_in[14];
    const float* g0  = (const float*)d_in[15];
    const float* be0 = (const float*)d_in[16];
    const float* g1  = (const float*)d_in[17];
    const float* be1 = (const float*)d_in[18];
    const float* g2  = (const float*)d_in[19];
    const float* be2 = (const float*)d_in[20];
    const float* g3  = (const float*)d_in[21];
    const float* be3 = (const float*)d_in[22];
    const float* fW  = (const float*)d_in[23];
    const float* fb  = (const float*)d_in[24];

    const int* ei0 = ei;
    const int* ei1 = ei + (size_t)N_NODES * KN;

    float*  ws  = (float*)d_ws;
    float*  x0  = ws + OFF_X0;
    unsigned short* xeh = (unsigned short*)(ws + OFF_XEH);
    uint4*  z1q1 = (uint4*)(ws + OFF_Z1Q);
    float4* S4  = (float4*)(ws + OFF_S4);
    float*  x2  = ws + OFF_X2;
    float*  y   = ws + OFF_Y;
    float*  TX  = ws + OFF_TX;
    float*  SS  = ws + OFF_SS;
    float*  X2S = ws + OFF_X2S;
    float*  YS  = ws + OFF_YS;
    float*  P   = ws + OFF_P;

    // zero all stats accumulators
    hipMemsetAsync(TX, 0, (OFF_P - OFF_TX) * sizeof(float), stream);

    // stage 0: BN0
    statsx_kernel<<<98, 256, 0, stream>>>((const float4*)x, TX);
    prep0_kernel<<<1, 1, 0, stream>>>(TX, P, g0, be0, W0, b0, aW0, ab0);
    x0_kernel<<<98, 256, 0, stream>>>((const float4*)x, P, (float4*)x0);

    // layer 0 (rank-1): S per node, fused S stats
    att0_kernel<<<N_NODES / 8, 256, 0, stream>>>(x0, ei0, ei1, (const float2*)e, P, S4, SS);

    // layer 1 (z-record scheme: 2 gather requests/edge, packed butterfly)
    prep1_kernel<<<1, 64, 0, stream>>>(SS, P, W0, g1, be1, W1, b1, aW1, ab1);
    zq1_kernel<<<(N_NODES + 255) / 256, 256, 0, stream>>>(x0, S4, P, aW1, z1q1);
    att_z1_kernel<<<N_NODES / 8, 256, 0, stream>>>(z1q1, ei0, ei1, P, x2, X2S);

    // layer 2 (packed butterfly)
    prep2_kernel<<<1, 64, 0, stream>>>(SS, X2S, P, W0, g1, be1, g2, be2, W2, b2);
    xe2_kernel<<<(N_NODES + 255) / 256, 256, 0, stream>>>(x0, S4, x2, P, aW2, xeh);
    att_big_kernel<<<N_NODES / 8, 256, 0, stream>>>(xeh, ei0, ei1, aW2, ab2, y, YS);

    // final BN3 + fc
    prepF_kernel<<<1, 64, 0, stream>>>(YS, P, g3, be3, fW, fb);
    final_kernel<<<(50000 + 255) / 256, 256, 0, stream>>>((const float4*)y, P, (float2*)d_out);
}